// Round 1
// baseline (396.737 us; speedup 1.0000x reference)
//
#include <hip/hip_runtime.h>
#include <math.h>

#define BB 2
#define LL 2048
#define DM 192
#define DI 384
#define DS 16
#define RK 12
#define NROW (BB*LL)      // 4096
#define NCH 16
#define CLEN (LL/NCH)     // 128

__device__ __forceinline__ float siluf(float v) { return v / (1.f + __expf(-v)); }

// ---------------- K1: residual add + RMSNorm ----------------
__global__ __launch_bounds__(256) void k_rmsnorm(
    const float* __restrict__ h, const float* __restrict__ r,
    const float* __restrict__ w, float* __restrict__ res, float* __restrict__ xn) {
  int row = blockIdx.x * 4 + (threadIdx.x >> 6);
  int lane = threadIdx.x & 63;
  const float* hp = h + row * DM;
  const float* rp = r + row * DM;
  float v0 = hp[lane]       + rp[lane];
  float v1 = hp[lane + 64]  + rp[lane + 64];
  float v2 = hp[lane + 128] + rp[lane + 128];
  float ss = v0 * v0 + v1 * v1 + v2 * v2;
  #pragma unroll
  for (int o = 32; o; o >>= 1) ss += __shfl_xor(ss, o);
  float inv = rsqrtf(ss * (1.f / DM) + 1e-5f);
  float* rr = res + row * DM;
  float* xo = xn + row * DM;
  rr[lane] = v0; rr[lane + 64] = v1; rr[lane + 128] = v2;
  xo[lane]       = v0 * inv * w[lane];
  xo[lane + 64]  = v1 * inv * w[lane + 64];
  xo[lane + 128] = v2 * inv * w[lane + 128];
}

// ---------------- K2: in_proj  xz = x @ W^T (768x192) ----------------
__global__ __launch_bounds__(256) void k_inproj(
    const float* __restrict__ xn, const float* __restrict__ wip,
    float* __restrict__ xh, float* __restrict__ z) {
  __shared__ float xs[DM][16];   // [k][r]
  int r0 = blockIdx.x * 16;
  for (int idx = threadIdx.x; idx < 16 * DM; idx += 256) {
    int r = idx & 15, k = idx >> 4;     // lane-contiguous LDS store
    xs[k][r] = xn[(r0 + r) * DM + k];
  }
  __syncthreads();
  for (int c = threadIdx.x; c < 2 * DI; c += 256) {
    const float* wr = wip + c * DM;
    float acc[16];
    #pragma unroll
    for (int i = 0; i < 16; i++) acc[i] = 0.f;
    for (int k = 0; k < DM; k++) {
      float wv = wr[k];
      const float4* xr = reinterpret_cast<const float4*>(&xs[k][0]);
      #pragma unroll
      for (int q = 0; q < 4; q++) {
        float4 a = xr[q];
        acc[4*q+0] += wv * a.x; acc[4*q+1] += wv * a.y;
        acc[4*q+2] += wv * a.z; acc[4*q+3] += wv * a.w;
      }
    }
    float* dst = (c < DI) ? (xh + c) : (z + (c - DI));
    #pragma unroll
    for (int r2 = 0; r2 < 16; r2++) dst[(r0 + r2) * DI] = acc[r2];
  }
}

// ---------------- K3a: causal depthwise conv + SiLU (both dirs) ----------------
__global__ __launch_bounds__(256) void k_conv(
    const float* __restrict__ xh,
    const float* __restrict__ cwf, const float* __restrict__ cbf,
    const float* __restrict__ cwb, const float* __restrict__ cbb,
    float* __restrict__ xc) {
  int dir = blockIdx.y;
  int g = blockIdx.x * 256 + threadIdx.x;
  int row = g / DI, d = g % DI;     // row = b*L + s (scan order)
  int b = row >> 11, s = row & (LL - 1);
  const float* cw = dir ? cwb : cwf;
  const float* cb = dir ? cbb : cbf;
  float acc = cb[d];
  #pragma unroll
  for (int k = 0; k < 4; k++) {
    int sp = s - 3 + k;
    if (sp >= 0) {
      int mr = b * LL + (dir ? (LL - 1 - sp) : sp);
      acc += cw[d * 4 + k] * xh[mr * DI + d];
    }
  }
  xc[(dir * NROW + row) * DI + d] = siluf(acc);
}

// ---------------- K3b: x_proj -> x_dbl; dt=softplus; emit B,C ----------------
__global__ __launch_bounds__(256) void k_xproj(
    const float* __restrict__ xc,
    const float* __restrict__ xpwf, const float* __restrict__ xpwb,
    const float* __restrict__ dtwf, const float* __restrict__ dtbf,
    const float* __restrict__ dtwb, const float* __restrict__ dtbb,
    float* __restrict__ dt, float* __restrict__ Bm, float* __restrict__ Cm) {
  int dir = blockIdx.y;
  int r0 = blockIdx.x * 16;
  const float* xpw = dir ? xpwb : xpwf;
  const float* dtw = dir ? dtwb : dtwf;
  const float* dtb = dir ? dtbb : dtbf;
  __shared__ float xs[16][DI];
  __shared__ float xd[16][44];
  for (int idx = threadIdx.x; idx < 16 * DI; idx += 256) {
    int r = idx / DI, d2 = idx % DI;
    xs[r][d2] = xc[(dir * NROW + r0 + r) * DI + d2];
  }
  __syncthreads();
  for (int o = threadIdx.x; o < 16 * 44; o += 256) {
    int r = o / 44, e = o % 44;
    const float* wr = xpw + e * DI;
    float a = 0.f;
    for (int d2 = 0; d2 < DI; d2++) a += xs[r][d2] * wr[d2];
    xd[r][e] = a;
  }
  __syncthreads();
  for (int o = threadIdx.x; o < 16 * DI; o += 256) {
    int r = o / DI, d2 = o % DI;
    float a = dtb[d2];
    const float* wr = dtw + d2 * RK;
    #pragma unroll
    for (int j = 0; j < RK; j++) a += xd[r][j] * wr[j];
    a = (a > 20.f) ? a : log1pf(__expf(a));
    dt[(dir * NROW + r0 + r) * DI + d2] = a;
  }
  for (int o = threadIdx.x; o < 16 * 32; o += 256) {
    int r = o / 32, j = o % 32;
    float v = xd[r][RK + j];
    if (j < DS) Bm[(dir * NROW + r0 + r) * DS + j] = v;
    else        Cm[(dir * NROW + r0 + r) * DS + (j - DS)] = v;
  }
}

// ---------------- S1: per-chunk local scan aggregates ----------------
__global__ __launch_bounds__(256) void k_scan1(
    const float* __restrict__ dt, const float* __restrict__ xc,
    const float* __restrict__ Bm,
    const float* __restrict__ Alf, const float* __restrict__ Alb,
    float* __restrict__ S, float* __restrict__ P) {
  int zb = blockIdx.z;              // dir*B + b
  int dir = zb >> 1;
  int n = threadIdx.x & 15;
  int dl = threadIdx.x >> 4;
  int d = blockIdx.x * 16 + dl;
  int c = blockIdx.y;
  const float* Al = dir ? Alb : Alf;
  float Av = -__expf(Al[d * DS + n]);
  int rowbase = zb * LL + c * CLEN;
  float hS = 0.f, sdt = 0.f;
  for (int s = 0; s < CLEN; s++) {
    int ro = rowbase + s;
    float dtv = dt[ro * DI + d];
    float xv  = xc[ro * DI + d];
    float Bv  = Bm[ro * DS + n];
    float dA = __expf(dtv * Av);
    hS = __fmaf_rn(dA, hS, dtv * xv * Bv);
    sdt += dtv;
  }
  int idx = ((zb * NCH + c) * DI + d) * DS + n;
  S[idx] = hS;
  P[idx] = __expf(Av * sdt);
}

// ---------------- S2: combine carries across chunks ----------------
__global__ __launch_bounds__(256) void k_scan2(
    const float* __restrict__ S, const float* __restrict__ P,
    float* __restrict__ Hin) {
  int g = blockIdx.x * 256 + threadIdx.x;   // 24576 chains
  int zb = g / (DI * DS);
  int rem = g % (DI * DS);
  float carry = 0.f;
  for (int c = 0; c < NCH; c++) {
    int idx = (zb * NCH + c) * (DI * DS) + rem;
    Hin[idx] = carry;
    carry = __fmaf_rn(P[idx], carry, S[idx]);
  }
}

// ---------------- S3: final per-chunk scan + y ----------------
__global__ __launch_bounds__(256) void k_scan3(
    const float* __restrict__ dt, const float* __restrict__ xc,
    const float* __restrict__ Bm, const float* __restrict__ Cm,
    const float* __restrict__ z, const float* __restrict__ Hin,
    const float* __restrict__ Alf, const float* __restrict__ Alb,
    const float* __restrict__ Df, const float* __restrict__ Db,
    float* __restrict__ y) {
  int zb = blockIdx.z;
  int dir = zb >> 1, b = zb & 1;
  int n = threadIdx.x & 15;
  int dl = threadIdx.x >> 4;
  int d = blockIdx.x * 16 + dl;
  int c = blockIdx.y;
  const float* Al = dir ? Alb : Alf;
  const float* Dp = dir ? Db : Df;
  float Av = -__expf(Al[d * DS + n]);
  float Dv = Dp[d];
  int rowbase = zb * LL + c * CLEN;
  int idx = ((zb * NCH + c) * DI + d) * DS + n;
  float h = Hin[idx];
  for (int s = 0; s < CLEN; s++) {
    int ro = rowbase + s;
    float dtv = dt[ro * DI + d];
    float xv  = xc[ro * DI + d];
    float Bv  = Bm[ro * DS + n];
    float Cv  = Cm[ro * DS + n];
    float dA = __expf(dtv * Av);
    h = __fmaf_rn(dA, h, dtv * xv * Bv);
    float p = h * Cv;
    p += __shfl_xor(p, 1); p += __shfl_xor(p, 2);
    p += __shfl_xor(p, 4); p += __shfl_xor(p, 8);
    if (n == 0) {
      int sg = c * CLEN + s;
      int mr = b * LL + (dir ? (LL - 1 - sg) : sg);
      float zv = z[mr * DI + d];
      float yv = (p + xv * Dv) * siluf(zv);
      y[ro * DI + d] = yv;
    }
  }
}

// ---------------- K5: out = (y_f + rev(y_b)) @ out_proj^T ----------------
__global__ __launch_bounds__(256) void k_outproj(
    const float* __restrict__ y, const float* __restrict__ wop,
    float* __restrict__ out) {
  __shared__ float ys[DI][16];    // [k][r]
  int r0 = blockIdx.x * 16;       // memory-order rows
  for (int idx = threadIdx.x; idx < 16 * DI; idx += 256) {
    int r = idx & 15, k = idx >> 4;   // lane-contiguous LDS store
    int row = r0 + r;
    int b = row >> 11, l = row & (LL - 1);
    float vf = y[(b * LL + l) * DI + k];
    float vb = y[((2 + b) * LL + (LL - 1 - l)) * DI + k];
    ys[k][r] = vf + vb;
  }
  __syncthreads();
  int c = threadIdx.x;
  if (c < DM) {
    const float* wr = wop + c * DI;
    float acc[16];
    #pragma unroll
    for (int i = 0; i < 16; i++) acc[i] = 0.f;
    for (int k = 0; k < DI; k++) {
      float wv = wr[k];
      const float4* xr = reinterpret_cast<const float4*>(&ys[k][0]);
      #pragma unroll
      for (int q = 0; q < 4; q++) {
        float4 a = xr[q];
        acc[4*q+0] += wv * a.x; acc[4*q+1] += wv * a.y;
        acc[4*q+2] += wv * a.z; acc[4*q+3] += wv * a.w;
      }
    }
    #pragma unroll
    for (int r2 = 0; r2 < 16; r2++) out[(r0 + r2) * DM + c] = acc[r2];
  }
}

extern "C" void kernel_launch(void* const* d_in, const int* in_sizes, int n_in,
                              void* d_out, int out_size, void* d_ws, size_t ws_size,
                              hipStream_t stream) {
  const float* hid  = (const float*)d_in[0];
  const float* res  = (const float*)d_in[1];
  const float* nw   = (const float*)d_in[2];
  const float* wip  = (const float*)d_in[3];
  const float* wop  = (const float*)d_in[4];
  const float* cwf  = (const float*)d_in[5];
  const float* cbf  = (const float*)d_in[6];
  const float* xpwf = (const float*)d_in[7];
  const float* dtwf = (const float*)d_in[8];
  const float* dtbf = (const float*)d_in[9];
  const float* Alf  = (const float*)d_in[10];
  const float* Df   = (const float*)d_in[11];
  const float* cwb  = (const float*)d_in[12];
  const float* cbb  = (const float*)d_in[13];
  const float* xpwb = (const float*)d_in[14];
  const float* dtwb = (const float*)d_in[15];
  const float* dtbb = (const float*)d_in[16];
  const float* Alb  = (const float*)d_in[17];
  const float* Db   = (const float*)d_in[18];

  float* out_p  = (float*)d_out;                  // (B,L,192)
  float* resid  = out_p + NROW * DM;              // (B,L,192)

  float* ws = (float*)d_ws;
  float* xn  = ws;                       // 786432
  float* xh  = xn  + NROW * DM;          // 1572864
  float* zz  = xh  + NROW * DI;          // 1572864
  float* xc  = zz  + NROW * DI;          // 2*1572864
  float* dt  = xc  + 2 * NROW * DI;      // 2*1572864
  float* Bm  = dt  + 2 * NROW * DI;      // 2*65536
  float* Cm  = Bm  + 2 * NROW * DS;      // 2*65536
  float* yy  = Cm  + 2 * NROW * DS;      // 2*1572864
  float* S   = yy  + 2 * NROW * DI;      // 393216
  float* P   = S   + 2 * BB * NCH * DI * DS;
  float* Hin = P   + 2 * BB * NCH * DI * DS;

  k_rmsnorm<<<NROW / 4, 256, 0, stream>>>(hid, res, nw, resid, xn);
  k_inproj<<<NROW / 16, 256, 0, stream>>>(xn, wip, xh, zz);
  k_conv<<<dim3(NROW * DI / 256, 2), 256, 0, stream>>>(xh, cwf, cbf, cwb, cbb, xc);
  k_xproj<<<dim3(NROW / 16, 2), 256, 0, stream>>>(xc, xpwf, xpwb, dtwf, dtbf, dtwb, dtbb,
                                                  dt, Bm, Cm);
  k_scan1<<<dim3(DI / 16, NCH, 2 * BB), 256, 0, stream>>>(dt, xc, Bm, Alf, Alb, S, P);
  k_scan2<<<(2 * BB * DI * DS) / 256, 256, 0, stream>>>(S, P, Hin);
  k_scan3<<<dim3(DI / 16, NCH, 2 * BB), 256, 0, stream>>>(dt, xc, Bm, Cm, zz, Hin,
                                                          Alf, Alb, Df, Db, yy);
  k_outproj<<<NROW / 16, 256, 0, stream>>>(yy, wop, out_p);
}

// Round 2
// 311.438 us; speedup vs baseline: 1.2739x; 1.2739x over previous
//
#include <hip/hip_runtime.h>
#include <math.h>

#define BB 2
#define LL 2048
#define DM 192
#define DI 384
#define DS 16
#define RK 12
#define NROW (BB*LL)      // 4096
#define NCH 64
#define CLEN (LL/NCH)     // 32

__device__ __forceinline__ float siluf(float v) { return v / (1.f + __expf(-v)); }

// ---------------- K1: residual add + RMSNorm ----------------
__global__ __launch_bounds__(256) void k_rmsnorm(
    const float* __restrict__ h, const float* __restrict__ r,
    const float* __restrict__ w, float* __restrict__ res, float* __restrict__ xn) {
  int row = blockIdx.x * 4 + (threadIdx.x >> 6);
  int lane = threadIdx.x & 63;
  const float* hp = h + row * DM;
  const float* rp = r + row * DM;
  float v0 = hp[lane]       + rp[lane];
  float v1 = hp[lane + 64]  + rp[lane + 64];
  float v2 = hp[lane + 128] + rp[lane + 128];
  float ss = v0 * v0 + v1 * v1 + v2 * v2;
  #pragma unroll
  for (int o = 32; o; o >>= 1) ss += __shfl_xor(ss, o);
  float inv = rsqrtf(ss * (1.f / DM) + 1e-5f);
  float* rr = res + row * DM;
  float* xo = xn + row * DM;
  rr[lane] = v0; rr[lane + 64] = v1; rr[lane + 128] = v2;
  xo[lane]       = v0 * inv * w[lane];
  xo[lane + 64]  = v1 * inv * w[lane + 64];
  xo[lane + 128] = v2 * inv * w[lane + 128];
}

// ---------------- K2: in_proj  xz = x @ W^T (768x192) ----------------
__global__ __launch_bounds__(256) void k_inproj(
    const float* __restrict__ xn, const float* __restrict__ wip,
    float* __restrict__ xh, float* __restrict__ z) {
  __shared__ float xs[DM][16];   // [k][r]
  int r0 = blockIdx.x * 16;
  for (int idx = threadIdx.x; idx < 16 * DM; idx += 256) {
    int r = idx & 15, k = idx >> 4;     // lane-contiguous LDS store
    xs[k][r] = xn[(r0 + r) * DM + k];
  }
  __syncthreads();
  for (int c = threadIdx.x; c < 2 * DI; c += 256) {
    const float* wr = wip + c * DM;
    float acc[16];
    #pragma unroll
    for (int i = 0; i < 16; i++) acc[i] = 0.f;
    for (int k = 0; k < DM; k++) {
      float wv = wr[k];
      const float4* xr = reinterpret_cast<const float4*>(&xs[k][0]);
      #pragma unroll
      for (int q = 0; q < 4; q++) {
        float4 a = xr[q];
        acc[4*q+0] += wv * a.x; acc[4*q+1] += wv * a.y;
        acc[4*q+2] += wv * a.z; acc[4*q+3] += wv * a.w;
      }
    }
    float* dst = (c < DI) ? (xh + c) : (z + (c - DI));
    #pragma unroll
    for (int r2 = 0; r2 < 16; r2++) dst[(r0 + r2) * DI] = acc[r2];
  }
}

// ---------------- K3a: causal depthwise conv + SiLU (both dirs) ----------------
__global__ __launch_bounds__(256) void k_conv(
    const float* __restrict__ xh,
    const float* __restrict__ cwf, const float* __restrict__ cbf,
    const float* __restrict__ cwb, const float* __restrict__ cbb,
    float* __restrict__ xc) {
  int dir = blockIdx.y;
  int g = blockIdx.x * 256 + threadIdx.x;
  int row = g / DI, d = g % DI;     // row = b*L + s (scan order)
  int b = row >> 11, s = row & (LL - 1);
  const float* cw = dir ? cwb : cwf;
  const float* cb = dir ? cbb : cbf;
  float acc = cb[d];
  #pragma unroll
  for (int k = 0; k < 4; k++) {
    int sp = s - 3 + k;
    if (sp >= 0) {
      int mr = b * LL + (dir ? (LL - 1 - sp) : sp);
      acc += cw[d * 4 + k] * xh[mr * DI + d];
    }
  }
  xc[(dir * NROW + row) * DI + d] = siluf(acc);
}

// ---------------- K3b: x_proj -> x_dbl; dt=softplus; emit B,C ----------------
__global__ __launch_bounds__(256) void k_xproj(
    const float* __restrict__ xc,
    const float* __restrict__ xpwf, const float* __restrict__ xpwb,
    const float* __restrict__ dtwf, const float* __restrict__ dtbf,
    const float* __restrict__ dtwb, const float* __restrict__ dtbb,
    float* __restrict__ dt, float* __restrict__ Bm, float* __restrict__ Cm) {
  int dir = blockIdx.y;
  int r0 = blockIdx.x * 16;
  const float* xpw = dir ? xpwb : xpwf;
  const float* dtw = dir ? dtwb : dtwf;
  const float* dtb = dir ? dtbb : dtbf;
  __shared__ float xs[16][DI];
  __shared__ float xd[16][44];
  for (int idx = threadIdx.x; idx < 16 * DI; idx += 256) {
    int r = idx / DI, d2 = idx % DI;
    xs[r][d2] = xc[(dir * NROW + r0 + r) * DI + d2];
  }
  __syncthreads();
  for (int o = threadIdx.x; o < 16 * 44; o += 256) {
    int r = o / 44, e = o % 44;
    const float4* wr = reinterpret_cast<const float4*>(xpw + e * DI);
    const float4* xr = reinterpret_cast<const float4*>(&xs[r][0]);
    float a = 0.f;
    #pragma unroll 4
    for (int q = 0; q < DI / 4; q++) {
      float4 w = wr[q], x = xr[q];
      a += w.x * x.x + w.y * x.y + w.z * x.z + w.w * x.w;
    }
    xd[r][e] = a;
  }
  __syncthreads();
  for (int o = threadIdx.x; o < 16 * DI; o += 256) {
    int r = o / DI, d2 = o % DI;
    float a = dtb[d2];
    const float* wr = dtw + d2 * RK;
    #pragma unroll
    for (int j = 0; j < RK; j++) a += xd[r][j] * wr[j];
    a = (a > 20.f) ? a : log1pf(__expf(a));
    dt[(dir * NROW + r0 + r) * DI + d2] = a;
  }
  for (int o = threadIdx.x; o < 16 * 32; o += 256) {
    int r = o / 32, j = o % 32;
    float v = xd[r][RK + j];
    if (j < DS) Bm[(dir * NROW + r0 + r) * DS + j] = v;
    else        Cm[(dir * NROW + r0 + r) * DS + (j - DS)] = v;
  }
}

// ---------------- S1: per-chunk local scan aggregates ----------------
// one thread per (zb, chunk, d); 16 n's in registers
__global__ __launch_bounds__(128) void k_scan1(
    const float* __restrict__ dt, const float* __restrict__ xc,
    const float* __restrict__ Bm,
    const float* __restrict__ Alf, const float* __restrict__ Alb,
    float* __restrict__ S, float* __restrict__ P) {
  int zb = blockIdx.z;              // dir*B + b
  int dir = zb >> 1;
  int d = blockIdx.x * 128 + threadIdx.x;
  int c = blockIdx.y;
  const float* Al = dir ? Alb : Alf;
  float Av[DS];
  {
    const float4* ap = reinterpret_cast<const float4*>(Al + d * DS);
    #pragma unroll
    for (int q = 0; q < 4; q++) {
      float4 a = ap[q];
      Av[4*q+0] = -__expf(a.x); Av[4*q+1] = -__expf(a.y);
      Av[4*q+2] = -__expf(a.z); Av[4*q+3] = -__expf(a.w);
    }
  }
  int rowbase = zb * LL + c * CLEN;
  const float4* Bp4 = reinterpret_cast<const float4*>(Bm + (size_t)rowbase * DS);
  float h[DS];
  #pragma unroll
  for (int n = 0; n < DS; n++) h[n] = 0.f;
  float sdt = 0.f;
  float dtv = dt[(size_t)rowbase * DI + d];
  float xv  = xc[(size_t)rowbase * DI + d];
  #pragma unroll 4
  for (int s = 0; s < CLEN; s++) {
    float dtn_ = 0.f, xn_ = 0.f;
    if (s + 1 < CLEN) {
      dtn_ = dt[(size_t)(rowbase + s + 1) * DI + d];
      xn_  = xc[(size_t)(rowbase + s + 1) * DI + d];
    }
    // block-uniform B row (scalarizes to s_load)
    float4 B0 = Bp4[s*4+0], B1 = Bp4[s*4+1], B2 = Bp4[s*4+2], B3 = Bp4[s*4+3];
    float Bv[DS] = {B0.x,B0.y,B0.z,B0.w, B1.x,B1.y,B1.z,B1.w,
                    B2.x,B2.y,B2.z,B2.w, B3.x,B3.y,B3.z,B3.w};
    float dtx = dtv * xv;
    sdt += dtv;
    #pragma unroll
    for (int n = 0; n < DS; n++) {
      float dA = __expf(dtv * Av[n]);
      h[n] = __fmaf_rn(dA, h[n], dtx * Bv[n]);
    }
    dtv = dtn_; xv = xn_;
  }
  size_t base = ((size_t)(zb * NCH + c) * DI + d) * DS;
  float4* Sp = reinterpret_cast<float4*>(S + base);
  float4* Pp = reinterpret_cast<float4*>(P + base);
  #pragma unroll
  for (int q = 0; q < 4; q++) {
    Sp[q] = make_float4(h[4*q+0], h[4*q+1], h[4*q+2], h[4*q+3]);
    Pp[q] = make_float4(__expf(Av[4*q+0]*sdt), __expf(Av[4*q+1]*sdt),
                        __expf(Av[4*q+2]*sdt), __expf(Av[4*q+3]*sdt));
  }
}

// ---------------- S2: combine carries across chunks (in-place: S -> Hin) ----------------
__global__ __launch_bounds__(256) void k_scan2(
    float* __restrict__ S, const float* __restrict__ P) {
  int g = blockIdx.x * 256 + threadIdx.x;   // 24576 chains
  int zb = g / (DI * DS);
  int rem = g % (DI * DS);
  const int stride = DI * DS;
  size_t base = (size_t)zb * NCH * stride + rem;
  float carry = 0.f;
  for (int c0 = 0; c0 < NCH; c0 += 8) {
    float p8[8], s8[8];
    #pragma unroll
    for (int j = 0; j < 8; j++) {
      p8[j] = P[base + (size_t)(c0 + j) * stride];
      s8[j] = S[base + (size_t)(c0 + j) * stride];
    }
    #pragma unroll
    for (int j = 0; j < 8; j++) {
      S[base + (size_t)(c0 + j) * stride] = carry;      // Hin for chunk c0+j
      carry = __fmaf_rn(p8[j], carry, s8[j]);
    }
  }
}

// ---------------- S3: final per-chunk scan + y ----------------
__global__ __launch_bounds__(128) void k_scan3(
    const float* __restrict__ dt, const float* __restrict__ xc,
    const float* __restrict__ Bm, const float* __restrict__ Cm,
    const float* __restrict__ z, const float* __restrict__ Hin,
    const float* __restrict__ Alf, const float* __restrict__ Alb,
    const float* __restrict__ Df, const float* __restrict__ Db,
    float* __restrict__ y) {
  int zb = blockIdx.z;
  int dir = zb >> 1, b = zb & 1;
  int d = blockIdx.x * 128 + threadIdx.x;
  int c = blockIdx.y;
  const float* Al = dir ? Alb : Alf;
  const float* Dp = dir ? Db : Df;
  float Av[DS];
  {
    const float4* ap = reinterpret_cast<const float4*>(Al + d * DS);
    #pragma unroll
    for (int q = 0; q < 4; q++) {
      float4 a = ap[q];
      Av[4*q+0] = -__expf(a.x); Av[4*q+1] = -__expf(a.y);
      Av[4*q+2] = -__expf(a.z); Av[4*q+3] = -__expf(a.w);
    }
  }
  float Dv = Dp[d];
  int rowbase = zb * LL + c * CLEN;
  const float4* Bp4 = reinterpret_cast<const float4*>(Bm + (size_t)rowbase * DS);
  const float4* Cp4 = reinterpret_cast<const float4*>(Cm + (size_t)rowbase * DS);
  size_t base = ((size_t)(zb * NCH + c) * DI + d) * DS;
  float h[DS];
  {
    const float4* hp = reinterpret_cast<const float4*>(Hin + base);
    #pragma unroll
    for (int q = 0; q < 4; q++) {
      float4 a = hp[q];
      h[4*q+0] = a.x; h[4*q+1] = a.y; h[4*q+2] = a.z; h[4*q+3] = a.w;
    }
  }
  float dtv = dt[(size_t)rowbase * DI + d];
  float xv  = xc[(size_t)rowbase * DI + d];
  #pragma unroll 4
  for (int s = 0; s < CLEN; s++) {
    float dtn_ = 0.f, xn_ = 0.f;
    if (s + 1 < CLEN) {
      dtn_ = dt[(size_t)(rowbase + s + 1) * DI + d];
      xn_  = xc[(size_t)(rowbase + s + 1) * DI + d];
    }
    float4 B0 = Bp4[s*4+0], B1 = Bp4[s*4+1], B2 = Bp4[s*4+2], B3 = Bp4[s*4+3];
    float Bv[DS] = {B0.x,B0.y,B0.z,B0.w, B1.x,B1.y,B1.z,B1.w,
                    B2.x,B2.y,B2.z,B2.w, B3.x,B3.y,B3.z,B3.w};
    float4 C0 = Cp4[s*4+0], C1 = Cp4[s*4+1], C2 = Cp4[s*4+2], C3 = Cp4[s*4+3];
    float Cv[DS] = {C0.x,C0.y,C0.z,C0.w, C1.x,C1.y,C1.z,C1.w,
                    C2.x,C2.y,C2.z,C2.w, C3.x,C3.y,C3.z,C3.w};
    float dtx = dtv * xv;
    float acc = xv * Dv;
    #pragma unroll
    for (int n = 0; n < DS; n++) {
      float dA = __expf(dtv * Av[n]);
      h[n] = __fmaf_rn(dA, h[n], dtx * Bv[n]);
      acc = __fmaf_rn(h[n], Cv[n], acc);
    }
    int sg = c * CLEN + s;
    int mr = b * LL + (dir ? (LL - 1 - sg) : sg);
    float zv = z[(size_t)mr * DI + d];
    y[(size_t)(rowbase + s) * DI + d] = acc * siluf(zv);
    dtv = dtn_; xv = xn_;
  }
}

// ---------------- K5: out = (y_f + rev(y_b)) @ out_proj^T ----------------
__global__ __launch_bounds__(256) void k_outproj(
    const float* __restrict__ y, const float* __restrict__ wop,
    float* __restrict__ out) {
  __shared__ float ys[DI][16];    // [k][r]
  int r0 = blockIdx.x * 16;       // memory-order rows
  for (int idx = threadIdx.x; idx < 16 * DI; idx += 256) {
    int r = idx & 15, k = idx >> 4;   // lane-contiguous LDS store
    int row = r0 + r;
    int b = row >> 11, l = row & (LL - 1);
    float vf = y[(b * LL + l) * DI + k];
    float vb = y[((2 + b) * LL + (LL - 1 - l)) * DI + k];
    ys[k][r] = vf + vb;
  }
  __syncthreads();
  int c = threadIdx.x;
  if (c < DM) {
    const float* wr = wop + c * DI;
    float acc[16];
    #pragma unroll
    for (int i = 0; i < 16; i++) acc[i] = 0.f;
    for (int k = 0; k < DI; k++) {
      float wv = wr[k];
      const float4* xr = reinterpret_cast<const float4*>(&ys[k][0]);
      #pragma unroll
      for (int q = 0; q < 4; q++) {
        float4 a = xr[q];
        acc[4*q+0] += wv * a.x; acc[4*q+1] += wv * a.y;
        acc[4*q+2] += wv * a.z; acc[4*q+3] += wv * a.w;
      }
    }
    #pragma unroll
    for (int r2 = 0; r2 < 16; r2++) out[(r0 + r2) * DM + c] = acc[r2];
  }
}

extern "C" void kernel_launch(void* const* d_in, const int* in_sizes, int n_in,
                              void* d_out, int out_size, void* d_ws, size_t ws_size,
                              hipStream_t stream) {
  const float* hid  = (const float*)d_in[0];
  const float* res  = (const float*)d_in[1];
  const float* nw   = (const float*)d_in[2];
  const float* wip  = (const float*)d_in[3];
  const float* wop  = (const float*)d_in[4];
  const float* cwf  = (const float*)d_in[5];
  const float* cbf  = (const float*)d_in[6];
  const float* xpwf = (const float*)d_in[7];
  const float* dtwf = (const float*)d_in[8];
  const float* dtbf = (const float*)d_in[9];
  const float* Alf  = (const float*)d_in[10];
  const float* Df   = (const float*)d_in[11];
  const float* cwb  = (const float*)d_in[12];
  const float* cbb  = (const float*)d_in[13];
  const float* xpwb = (const float*)d_in[14];
  const float* dtwb = (const float*)d_in[15];
  const float* dtbb = (const float*)d_in[16];
  const float* Alb  = (const float*)d_in[17];
  const float* Db   = (const float*)d_in[18];

  float* out_p  = (float*)d_out;                  // (B,L,192)
  float* resid  = out_p + NROW * DM;              // (B,L,192)

  float* ws = (float*)d_ws;
  float* xn  = ws;                       // 786432
  float* xh  = xn  + NROW * DM;          // 1572864
  float* zz  = xh  + NROW * DI;          // 1572864
  float* xc  = zz  + NROW * DI;          // 2*1572864
  float* dt  = xc  + 2 * NROW * DI;      // 2*1572864
  float* Bm  = dt  + 2 * NROW * DI;      // 2*65536
  float* Cm  = Bm  + 2 * NROW * DS;      // 2*65536
  float* yy  = Cm  + 2 * NROW * DS;      // 2*1572864
  float* S   = yy  + 2 * NROW * DI;      // 4*64*384*16 = 1572864
  float* P   = S   + 2 * BB * NCH * DI * DS;  // 1572864

  k_rmsnorm<<<NROW / 4, 256, 0, stream>>>(hid, res, nw, resid, xn);
  k_inproj<<<NROW / 16, 256, 0, stream>>>(xn, wip, xh, zz);
  k_conv<<<dim3(NROW * DI / 256, 2), 256, 0, stream>>>(xh, cwf, cbf, cwb, cbb, xc);
  k_xproj<<<dim3(NROW / 16, 2), 256, 0, stream>>>(xc, xpwf, xpwb, dtwf, dtbf, dtwb, dtbb,
                                                  dt, Bm, Cm);
  k_scan1<<<dim3(DI / 128, NCH, 2 * BB), 128, 0, stream>>>(dt, xc, Bm, Alf, Alb, S, P);
  k_scan2<<<(2 * BB * DI * DS) / 256, 256, 0, stream>>>(S, P);
  k_scan3<<<dim3(DI / 128, NCH, 2 * BB), 128, 0, stream>>>(dt, xc, Bm, Cm, zz, S,
                                                           Alf, Alb, Df, Db, yy);
  k_outproj<<<NROW / 16, 256, 0, stream>>>(yy, wop, out_p);
}

// Round 4
// 286.838 us; speedup vs baseline: 1.3831x; 1.0858x over previous
//
#include <hip/hip_runtime.h>
#include <math.h>

#define BB 2
#define LL 2048
#define DM 192
#define DI 384
#define DS 16
#define RK 12
#define NROW (BB*LL)      // 4096
#define NCH 64
#define CLEN (LL/NCH)     // 32
#define EP 48             // padded x_proj output cols (44 -> 48)

__device__ __forceinline__ float siluf(float v) { return v / (1.f + __expf(-v)); }

// ---------------- K0: transpose weights to k-major layouts ----------------
// wt_in[k][c]   : 192 x 768   (from in_proj_w [768][192])
// wt_out[k][c]  : 384 x 192   (from out_proj_w [192][384])
// wt_xp[dir][k][e(48)] : 2 x 384 x 48 (from x_proj_w [44][384], zero-padded)
// wt_dt[dir][j][d]     : 2 x 12 x 384 (from dt_w [384][12])
#define N_IN  (DM * 2 * DI)          // 147456
#define N_OUT (DI * DM)              // 73728
#define N_XP  (2 * DI * EP)          // 36864
#define N_DT  (2 * RK * DI)          // 9216
#define N_PREP (N_IN + N_OUT + N_XP + N_DT)

__global__ __launch_bounds__(256) void k_wprep(
    const float* __restrict__ wip, const float* __restrict__ wop,
    const float* __restrict__ xpwf, const float* __restrict__ xpwb,
    const float* __restrict__ dtwf, const float* __restrict__ dtwb,
    float* __restrict__ wt_in, float* __restrict__ wt_out,
    float* __restrict__ wt_xp, float* __restrict__ wt_dt) {
  int i = blockIdx.x * 256 + threadIdx.x;
  if (i < N_IN) {
    int k = i / (2 * DI), c = i % (2 * DI);
    wt_in[i] = wip[c * DM + k];
  } else if (i < N_IN + N_OUT) {
    int t = i - N_IN;
    int k = t / DM, c = t % DM;
    wt_out[t] = wop[c * DI + k];
  } else if (i < N_IN + N_OUT + N_XP) {
    int t = i - N_IN - N_OUT;
    int dir = t / (DI * EP), rem = t % (DI * EP);
    int k = rem / EP, e = rem % EP;
    const float* src = dir ? xpwb : xpwf;
    wt_xp[t] = (e < RK + 2 * DS) ? src[e * DI + k] : 0.f;
  } else if (i < N_PREP) {
    int t = i - N_IN - N_OUT - N_XP;
    int dir = t / (RK * DI), rem = t % (RK * DI);
    int j = rem / DI, d = rem % DI;
    const float* src = dir ? dtwb : dtwf;
    wt_dt[t] = src[d * RK + j];
  }
}

// ---------------- K1: residual add + RMSNorm ----------------
__global__ __launch_bounds__(256) void k_rmsnorm(
    const float* __restrict__ h, const float* __restrict__ r,
    const float* __restrict__ w, float* __restrict__ res, float* __restrict__ xn) {
  int row = blockIdx.x * 4 + (threadIdx.x >> 6);
  int lane = threadIdx.x & 63;
  const float* hp = h + row * DM;
  const float* rp = r + row * DM;
  float v0 = hp[lane]       + rp[lane];
  float v1 = hp[lane + 64]  + rp[lane + 64];
  float v2 = hp[lane + 128] + rp[lane + 128];
  float ss = v0 * v0 + v1 * v1 + v2 * v2;
  #pragma unroll
  for (int o = 32; o; o >>= 1) ss += __shfl_xor(ss, o);
  float inv = rsqrtf(ss * (1.f / DM) + 1e-5f);
  float* rr = res + row * DM;
  float* xo = xn + row * DM;
  rr[lane] = v0; rr[lane + 64] = v1; rr[lane + 128] = v2;
  xo[lane]       = v0 * inv * w[lane];
  xo[lane + 64]  = v1 * inv * w[lane + 64];
  xo[lane + 128] = v2 * inv * w[lane + 128];
}

// ---------------- K2: in_proj  xz = x @ W^T (768x192), W pre-transposed ----------------
__global__ __launch_bounds__(256) void k_inproj(
    const float* __restrict__ xn, const float* __restrict__ wt,
    float* __restrict__ xh, float* __restrict__ z) {
  __shared__ float xs[DM][16];   // [k][r]
  int r0 = blockIdx.x * 16;
  for (int idx = threadIdx.x; idx < 16 * DM; idx += 256) {
    int r = idx & 15, k = idx >> 4;     // lane-contiguous LDS store
    xs[k][r] = xn[(r0 + r) * DM + k];
  }
  __syncthreads();
  for (int c = threadIdx.x; c < 2 * DI; c += 256) {
    const float* wc = wt + c;           // stride 768 along k, coalesced across lanes
    float acc[16];
    #pragma unroll
    for (int i = 0; i < 16; i++) acc[i] = 0.f;
    for (int k = 0; k < DM; k++) {
      float wv = wc[k * (2 * DI)];
      const float4* xr = reinterpret_cast<const float4*>(&xs[k][0]);
      #pragma unroll
      for (int q = 0; q < 4; q++) {
        float4 a = xr[q];
        acc[4*q+0] += wv * a.x; acc[4*q+1] += wv * a.y;
        acc[4*q+2] += wv * a.z; acc[4*q+3] += wv * a.w;
      }
    }
    float* dst = (c < DI) ? (xh + c) : (z + (c - DI));
    #pragma unroll
    for (int r2 = 0; r2 < 16; r2++) dst[(r0 + r2) * DI] = acc[r2];
  }
}

// ---------------- K3a: causal depthwise conv + SiLU (both dirs) ----------------
__global__ __launch_bounds__(256) void k_conv(
    const float* __restrict__ xh,
    const float* __restrict__ cwf, const float* __restrict__ cbf,
    const float* __restrict__ cwb, const float* __restrict__ cbb,
    float* __restrict__ xc) {
  int dir = blockIdx.y;
  int g = blockIdx.x * 256 + threadIdx.x;
  int row = g / DI, d = g % DI;     // row = b*L + s (scan order)
  int b = row >> 11, s = row & (LL - 1);
  const float* cw = dir ? cwb : cwf;
  const float* cb = dir ? cbb : cbf;
  float acc = cb[d];
  #pragma unroll
  for (int k = 0; k < 4; k++) {
    int sp = s - 3 + k;
    if (sp >= 0) {
      int mr = b * LL + (dir ? (LL - 1 - sp) : sp);
      acc += cw[d * 4 + k] * xh[mr * DI + d];
    }
  }
  xc[(dir * NROW + row) * DI + d] = siluf(acc);
}

// ---------------- K3b: x_proj -> x_dbl; dt=softplus; emit B,C (transposed W) ----------------
__global__ __launch_bounds__(256) void k_xproj(
    const float* __restrict__ xc,
    const float* __restrict__ wt_xp, const float* __restrict__ wt_dt,
    const float* __restrict__ dtbf, const float* __restrict__ dtbb,
    float* __restrict__ dt, float* __restrict__ Bm, float* __restrict__ Cm) {
  int dir = blockIdx.y;
  int r0 = blockIdx.x * 16;
  const float* wxp = wt_xp + dir * DI * EP;   // [k][48]
  const float* wdt = wt_dt + dir * RK * DI;   // [j][384]
  const float* dtb = dir ? dtbb : dtbf;
  __shared__ float xs[16][DI];
  __shared__ float xd[16][EP];
  for (int idx = threadIdx.x; idx < 16 * DI; idx += 256) {
    int r = idx / DI, d2 = idx % DI;
    xs[r][d2] = xc[(size_t)(dir * NROW + r0 + r) * DI + d2];
  }
  __syncthreads();
  // x_dbl: 16 rows x 48 cols (top 4 are zero-padded), K = 384
  for (int o = threadIdx.x; o < 16 * EP; o += 256) {
    int r = o / EP, e = o % EP;
    const float* wcol = wxp + e;           // stride EP along k, coalesced across lanes
    const float4* xr = reinterpret_cast<const float4*>(&xs[r][0]);
    float ax = 0.f, ay = 0.f, az = 0.f, aw = 0.f;   // 4 independent chains
    #pragma unroll 4
    for (int q = 0; q < DI / 4; q++) {
      float4 x = xr[q];
      ax += wcol[(4*q+0) * EP] * x.x;
      ay += wcol[(4*q+1) * EP] * x.y;
      az += wcol[(4*q+2) * EP] * x.z;
      aw += wcol[(4*q+3) * EP] * x.w;
    }
    xd[r][e] = (ax + ay) + (az + aw);
  }
  __syncthreads();
  for (int o = threadIdx.x; o < 16 * DI; o += 256) {
    int r = o / DI, d2 = o % DI;
    float a = dtb[d2];
    #pragma unroll
    for (int j = 0; j < RK; j++) a += xd[r][j] * wdt[j * DI + d2];
    a = (a > 20.f) ? a : log1pf(__expf(a));
    dt[(size_t)(dir * NROW + r0 + r) * DI + d2] = a;
  }
  for (int o = threadIdx.x; o < 16 * 32; o += 256) {
    int r = o / 32, j = o % 32;
    float v = xd[r][RK + j];
    if (j < DS) Bm[(size_t)(dir * NROW + r0 + r) * DS + j] = v;
    else        Cm[(size_t)(dir * NROW + r0 + r) * DS + (j - DS)] = v;
  }
}

// ---------------- S1: per-chunk local scan aggregates ----------------
__global__ __launch_bounds__(128) void k_scan1(
    const float* __restrict__ dt, const float* __restrict__ xc,
    const float* __restrict__ Bm,
    const float* __restrict__ Alf, const float* __restrict__ Alb,
    float* __restrict__ S, float* __restrict__ P) {
  int zb = blockIdx.z;              // dir*B + b
  int dir = zb >> 1;
  int d = blockIdx.x * 128 + threadIdx.x;
  int c = blockIdx.y;
  const float* Al = dir ? Alb : Alf;
  float Av[DS];
  {
    const float4* ap = reinterpret_cast<const float4*>(Al + d * DS);
    #pragma unroll
    for (int q = 0; q < 4; q++) {
      float4 a = ap[q];
      Av[4*q+0] = -__expf(a.x); Av[4*q+1] = -__expf(a.y);
      Av[4*q+2] = -__expf(a.z); Av[4*q+3] = -__expf(a.w);
    }
  }
  int rowbase = zb * LL + c * CLEN;
  const float4* Bp4 = reinterpret_cast<const float4*>(Bm + (size_t)rowbase * DS);
  float h[DS];
  #pragma unroll
  for (int n = 0; n < DS; n++) h[n] = 0.f;
  float sdt = 0.f;
  float dtv = dt[(size_t)rowbase * DI + d];
  float xv  = xc[(size_t)rowbase * DI + d];
  #pragma unroll 4
  for (int s = 0; s < CLEN; s++) {
    float dtn_ = 0.f, xn_ = 0.f;
    if (s + 1 < CLEN) {
      dtn_ = dt[(size_t)(rowbase + s + 1) * DI + d];
      xn_  = xc[(size_t)(rowbase + s + 1) * DI + d];
    }
    float4 B0 = Bp4[s*4+0], B1 = Bp4[s*4+1], B2 = Bp4[s*4+2], B3 = Bp4[s*4+3];
    float Bv[DS] = {B0.x,B0.y,B0.z,B0.w, B1.x,B1.y,B1.z,B1.w,
                    B2.x,B2.y,B2.z,B2.w, B3.x,B3.y,B3.z,B3.w};
    float dtx = dtv * xv;
    sdt += dtv;
    #pragma unroll
    for (int n = 0; n < DS; n++) {
      float dA = __expf(dtv * Av[n]);
      h[n] = __fmaf_rn(dA, h[n], dtx * Bv[n]);
    }
    dtv = dtn_; xv = xn_;
  }
  size_t base = ((size_t)(zb * NCH + c) * DI + d) * DS;
  float4* Sp = reinterpret_cast<float4*>(S + base);
  float4* Pp = reinterpret_cast<float4*>(P + base);
  #pragma unroll
  for (int q = 0; q < 4; q++) {
    Sp[q] = make_float4(h[4*q+0], h[4*q+1], h[4*q+2], h[4*q+3]);
    Pp[q] = make_float4(__expf(Av[4*q+0]*sdt), __expf(Av[4*q+1]*sdt),
                        __expf(Av[4*q+2]*sdt), __expf(Av[4*q+3]*sdt));
  }
}

// ---------------- S2: combine carries across chunks (in-place: S -> Hin) ----------------
__global__ __launch_bounds__(256) void k_scan2(
    float* __restrict__ S, const float* __restrict__ P) {
  int g = blockIdx.x * 256 + threadIdx.x;   // 24576 chains
  int zb = g / (DI * DS);
  int rem = g % (DI * DS);
  const int stride = DI * DS;
  size_t base = (size_t)zb * NCH * stride + rem;
  float carry = 0.f;
  for (int c0 = 0; c0 < NCH; c0 += 8) {
    float p8[8], s8[8];
    #pragma unroll
    for (int j = 0; j < 8; j++) {
      p8[j] = P[base + (size_t)(c0 + j) * stride];
      s8[j] = S[base + (size_t)(c0 + j) * stride];
    }
    #pragma unroll
    for (int j = 0; j < 8; j++) {
      S[base + (size_t)(c0 + j) * stride] = carry;      // Hin for chunk c0+j
      carry = __fmaf_rn(p8[j], carry, s8[j]);
    }
  }
}

// ---------------- S3: final per-chunk scan + y ----------------
__global__ __launch_bounds__(128) void k_scan3(
    const float* __restrict__ dt, const float* __restrict__ xc,
    const float* __restrict__ Bm, const float* __restrict__ Cm,
    const float* __restrict__ z, const float* __restrict__ Hin,
    const float* __restrict__ Alf, const float* __restrict__ Alb,
    const float* __restrict__ Df, const float* __restrict__ Db,
    float* __restrict__ y) {
  int zb = blockIdx.z;
  int dir = zb >> 1, b = zb & 1;
  int d = blockIdx.x * 128 + threadIdx.x;
  int c = blockIdx.y;
  const float* Al = dir ? Alb : Alf;
  const float* Dp = dir ? Db : Df;
  float Av[DS];
  {
    const float4* ap = reinterpret_cast<const float4*>(Al + d * DS);
    #pragma unroll
    for (int q = 0; q < 4; q++) {
      float4 a = ap[q];
      Av[4*q+0] = -__expf(a.x); Av[4*q+1] = -__expf(a.y);
      Av[4*q+2] = -__expf(a.z); Av[4*q+3] = -__expf(a.w);
    }
  }
  float Dv = Dp[d];
  int rowbase = zb * LL + c * CLEN;
  const float4* Bp4 = reinterpret_cast<const float4*>(Bm + (size_t)rowbase * DS);
  const float4* Cp4 = reinterpret_cast<const float4*>(Cm + (size_t)rowbase * DS);
  size_t base = ((size_t)(zb * NCH + c) * DI + d) * DS;
  float h[DS];
  {
    const float4* hp = reinterpret_cast<const float4*>(Hin + base);
    #pragma unroll
    for (int q = 0; q < 4; q++) {
      float4 a = hp[q];
      h[4*q+0] = a.x; h[4*q+1] = a.y; h[4*q+2] = a.z; h[4*q+3] = a.w;
    }
  }
  float dtv = dt[(size_t)rowbase * DI + d];
  float xv  = xc[(size_t)rowbase * DI + d];
  #pragma unroll 4
  for (int s = 0; s < CLEN; s++) {
    float dtn_ = 0.f, xn_ = 0.f;
    if (s + 1 < CLEN) {
      dtn_ = dt[(size_t)(rowbase + s + 1) * DI + d];
      xn_  = xc[(size_t)(rowbase + s + 1) * DI + d];
    }
    float4 B0 = Bp4[s*4+0], B1 = Bp4[s*4+1], B2 = Bp4[s*4+2], B3 = Bp4[s*4+3];
    float Bv[DS] = {B0.x,B0.y,B0.z,B0.w, B1.x,B1.y,B1.z,B1.w,
                    B2.x,B2.y,B2.z,B2.w, B3.x,B3.y,B3.z,B3.w};
    float4 C0 = Cp4[s*4+0], C1 = Cp4[s*4+1], C2 = Cp4[s*4+2], C3 = Cp4[s*4+3];
    float Cv[DS] = {C0.x,C0.y,C0.z,C0.w, C1.x,C1.y,C1.z,C1.w,
                    C2.x,C2.y,C2.z,C2.w, C3.x,C3.y,C3.z,C3.w};
    float dtx = dtv * xv;
    float acc = xv * Dv;
    #pragma unroll
    for (int n = 0; n < DS; n++) {
      float dA = __expf(dtv * Av[n]);
      h[n] = __fmaf_rn(dA, h[n], dtx * Bv[n]);
      acc = __fmaf_rn(h[n], Cv[n], acc);
    }
    int sg = c * CLEN + s;
    int mr = b * LL + (dir ? (LL - 1 - sg) : sg);
    float zv = z[(size_t)mr * DI + d];
    y[(size_t)(rowbase + s) * DI + d] = acc * siluf(zv);
    dtv = dtn_; xv = xn_;
  }
}

// ---------------- K5: out = (y_f + rev(y_b)) @ out_proj^T (transposed W) ----------------
__global__ __launch_bounds__(192) void k_outproj(
    const float* __restrict__ y, const float* __restrict__ wt,
    float* __restrict__ out) {
  __shared__ float ys[DI][16];    // [k][r]
  int r0 = blockIdx.x * 16;       // memory-order rows
  for (int idx = threadIdx.x; idx < 16 * DI; idx += 192) {
    int r = idx & 15, k = idx >> 4;   // lane-contiguous LDS store
    int row = r0 + r;
    int b = row >> 11, l = row & (LL - 1);
    float vf = y[(size_t)(b * LL + l) * DI + k];
    float vb = y[(size_t)((2 + b) * LL + (LL - 1 - l)) * DI + k];
    ys[k][r] = vf + vb;
  }
  __syncthreads();
  int c = threadIdx.x;            // 192 threads = 192 output cols
  const float* wc = wt + c;       // stride 192 along k, coalesced across lanes
  float acc[16];
  #pragma unroll
  for (int i = 0; i < 16; i++) acc[i] = 0.f;
  for (int k = 0; k < DI; k++) {
    float wv = wc[k * DM];
    const float4* xr = reinterpret_cast<const float4*>(&ys[k][0]);
    #pragma unroll
    for (int q = 0; q < 4; q++) {
      float4 a = xr[q];
      acc[4*q+0] += wv * a.x; acc[4*q+1] += wv * a.y;
      acc[4*q+2] += wv * a.z; acc[4*q+3] += wv * a.w;
    }
  }
  #pragma unroll
  for (int r2 = 0; r2 < 16; r2++) out[(r0 + r2) * DM + c] = acc[r2];
}

extern "C" void kernel_launch(void* const* d_in, const int* in_sizes, int n_in,
                              void* d_out, int out_size, void* d_ws, size_t ws_size,
                              hipStream_t stream) {
  const float* hid  = (const float*)d_in[0];
  const float* res  = (const float*)d_in[1];
  const float* nw   = (const float*)d_in[2];
  const float* wip  = (const float*)d_in[3];
  const float* wop  = (const float*)d_in[4];
  const float* cwf  = (const float*)d_in[5];
  const float* cbf  = (const float*)d_in[6];
  const float* xpwf = (const float*)d_in[7];
  const float* dtwf = (const float*)d_in[8];
  const float* dtbf = (const float*)d_in[9];
  const float* Alf  = (const float*)d_in[10];
  const float* Df   = (const float*)d_in[11];
  const float* cwb  = (const float*)d_in[12];
  const float* cbb  = (const float*)d_in[13];
  const float* xpwb = (const float*)d_in[14];
  const float* dtwb = (const float*)d_in[15];
  const float* dtbb = (const float*)d_in[16];
  const float* Alb  = (const float*)d_in[17];
  const float* Db   = (const float*)d_in[18];

  float* out_p  = (float*)d_out;                  // (B,L,192)
  float* resid  = out_p + NROW * DM;              // (B,L,192)

  float* ws = (float*)d_ws;
  float* xn  = ws;                       // 786432
  float* xh  = xn  + NROW * DM;          // 1572864
  float* zz  = xh  + NROW * DI;          // 1572864
  float* xc  = zz  + NROW * DI;          // 2*1572864
  float* dt  = xc  + 2 * NROW * DI;      // 2*1572864
  float* Bm  = dt  + 2 * NROW * DI;      // 2*65536
  float* Cm  = Bm  + 2 * NROW * DS;      // 2*65536
  float* yy  = Cm  + 2 * NROW * DS;      // 2*1572864
  float* S   = yy  + 2 * NROW * DI;      // 1572864
  float* P   = S   + 2 * BB * NCH * DI * DS;  // 1572864
  float* wt_in  = P     + 2 * BB * NCH * DI * DS;
  float* wt_out = wt_in  + N_IN;
  float* wt_xp  = wt_out + N_OUT;
  float* wt_dt  = wt_xp  + N_XP;

  k_wprep<<<(N_PREP + 255) / 256, 256, 0, stream>>>(wip, wop, xpwf, xpwb, dtwf, dtwb,
                                                    wt_in, wt_out, wt_xp, wt_dt);
  k_rmsnorm<<<NROW / 4, 256, 0, stream>>>(hid, res, nw, resid, xn);
  k_inproj<<<NROW / 16, 256, 0, stream>>>(xn, wt_in, xh, zz);
  k_conv<<<dim3(NROW * DI / 256, 2), 256, 0, stream>>>(xh, cwf, cbf, cwb, cbb, xc);
  k_xproj<<<dim3(NROW / 16, 2), 256, 0, stream>>>(xc, wt_xp, wt_dt, dtbf, dtbb,
                                                  dt, Bm, Cm);
  k_scan1<<<dim3(DI / 128, NCH, 2 * BB), 128, 0, stream>>>(dt, xc, Bm, Alf, Alb, S, P);
  k_scan2<<<(2 * BB * DI * DS) / 256, 256, 0, stream>>>(S, P);
  k_scan3<<<dim3(DI / 128, NCH, 2 * BB), 128, 0, stream>>>(dt, xc, Bm, Cm, zz, S,
                                                           Alf, Alb, Df, Db, yy);
  k_outproj<<<NROW / 16, 192, 0, stream>>>(yy, wt_out, out_p);
}

// Round 5
// 258.053 us; speedup vs baseline: 1.5374x; 1.1115x over previous
//
#include <hip/hip_runtime.h>
#include <math.h>

#define BB 2
#define LL 2048
#define DM 192
#define DI 384
#define DS 16
#define RK 12
#define NROW (BB*LL)      // 4096
#define NCH 64
#define CLEN (LL/NCH)     // 32
#define EP 48             // padded x_proj output cols (44 -> 48)

__device__ __forceinline__ float siluf(float v) { return v / (1.f + __expf(-v)); }

// ---------------- K0: transpose weights to k-major layouts ----------------
#define N_IN  (DM * 2 * DI)          // 147456
#define N_OUT (DI * DM)              // 73728
#define N_XP  (2 * DI * EP)          // 36864
#define N_DT  (2 * RK * DI)          // 9216
#define N_PREP (N_IN + N_OUT + N_XP + N_DT)

__global__ __launch_bounds__(256) void k_wprep(
    const float* __restrict__ wip, const float* __restrict__ wop,
    const float* __restrict__ xpwf, const float* __restrict__ xpwb,
    const float* __restrict__ dtwf, const float* __restrict__ dtwb,
    float* __restrict__ wt_in, float* __restrict__ wt_out,
    float* __restrict__ wt_xp, float* __restrict__ wt_dt) {
  int i = blockIdx.x * 256 + threadIdx.x;
  if (i < N_IN) {
    int k = i / (2 * DI), c = i % (2 * DI);
    wt_in[i] = wip[c * DM + k];
  } else if (i < N_IN + N_OUT) {
    int t = i - N_IN;
    int k = t / DM, c = t % DM;
    wt_out[t] = wop[c * DI + k];
  } else if (i < N_IN + N_OUT + N_XP) {
    int t = i - N_IN - N_OUT;
    int dir = t / (DI * EP), rem = t % (DI * EP);
    int k = rem / EP, e = rem % EP;
    const float* src = dir ? xpwb : xpwf;
    wt_xp[t] = (e < RK + 2 * DS) ? src[e * DI + k] : 0.f;
  } else if (i < N_PREP) {
    int t = i - N_IN - N_OUT - N_XP;
    int dir = t / (RK * DI), rem = t % (RK * DI);
    int j = rem / DI, d = rem % DI;
    const float* src = dir ? dtwb : dtwf;
    wt_dt[t] = src[d * RK + j];
  }
}

// ---------------- K1: residual add + RMSNorm ----------------
__global__ __launch_bounds__(256) void k_rmsnorm(
    const float* __restrict__ h, const float* __restrict__ r,
    const float* __restrict__ w, float* __restrict__ res, float* __restrict__ xn) {
  int row = blockIdx.x * 4 + (threadIdx.x >> 6);
  int lane = threadIdx.x & 63;
  const float* hp = h + row * DM;
  const float* rp = r + row * DM;
  float v0 = hp[lane]       + rp[lane];
  float v1 = hp[lane + 64]  + rp[lane + 64];
  float v2 = hp[lane + 128] + rp[lane + 128];
  float ss = v0 * v0 + v1 * v1 + v2 * v2;
  #pragma unroll
  for (int o = 32; o; o >>= 1) ss += __shfl_xor(ss, o);
  float inv = rsqrtf(ss * (1.f / DM) + 1e-5f);
  float* rr = res + row * DM;
  float* xo = xn + row * DM;
  rr[lane] = v0; rr[lane + 64] = v1; rr[lane + 128] = v2;
  xo[lane]       = v0 * inv * w[lane];
  xo[lane + 64]  = v1 * inv * w[lane + 64];
  xo[lane + 128] = v2 * inv * w[lane + 128];
}

// ---------------- K2: in_proj  xz = x @ W^T, W pre-transposed ----------------
// grid: (row-tiles, 3 col-tiles); each thread one column, 16 rows
__global__ __launch_bounds__(256) void k_inproj(
    const float* __restrict__ xn, const float* __restrict__ wt,
    float* __restrict__ xh, float* __restrict__ z) {
  __shared__ float xs[DM][16];   // [k][r]
  int r0 = blockIdx.x * 16;
  int c = blockIdx.y * 256 + threadIdx.x;
  for (int idx = threadIdx.x; idx < 16 * DM; idx += 256) {
    int r = idx & 15, k = idx >> 4;     // lane-contiguous LDS store
    xs[k][r] = xn[(r0 + r) * DM + k];
  }
  __syncthreads();
  const float* wc = wt + c;             // stride 768 along k, coalesced across lanes
  float acc[16];
  #pragma unroll
  for (int i = 0; i < 16; i++) acc[i] = 0.f;
  for (int k = 0; k < DM; k += 4) {
    float w0 = wc[(k+0) * (2*DI)];
    float w1 = wc[(k+1) * (2*DI)];
    float w2 = wc[(k+2) * (2*DI)];
    float w3 = wc[(k+3) * (2*DI)];
    float wv4[4] = {w0, w1, w2, w3};
    #pragma unroll
    for (int kk = 0; kk < 4; kk++) {
      float wv = wv4[kk];
      const float4* xr = reinterpret_cast<const float4*>(&xs[k + kk][0]);
      #pragma unroll
      for (int q = 0; q < 4; q++) {
        float4 a = xr[q];
        acc[4*q+0] += wv * a.x; acc[4*q+1] += wv * a.y;
        acc[4*q+2] += wv * a.z; acc[4*q+3] += wv * a.w;
      }
    }
  }
  float* dst = (c < DI) ? (xh + c) : (z + (c - DI));
  #pragma unroll
  for (int r2 = 0; r2 < 16; r2++) dst[(r0 + r2) * DI] = acc[r2];
}

// ---------------- K3a: causal depthwise conv + SiLU (both dirs) ----------------
__global__ __launch_bounds__(256) void k_conv(
    const float* __restrict__ xh,
    const float* __restrict__ cwf, const float* __restrict__ cbf,
    const float* __restrict__ cwb, const float* __restrict__ cbb,
    float* __restrict__ xc) {
  int dir = blockIdx.y;
  int g = blockIdx.x * 256 + threadIdx.x;
  int row = g / DI, d = g % DI;     // row = b*L + s (scan order)
  int b = row >> 11, s = row & (LL - 1);
  const float* cw = dir ? cwb : cwf;
  const float* cb = dir ? cbb : cbf;
  float acc = cb[d];
  #pragma unroll
  for (int k = 0; k < 4; k++) {
    int sp = s - 3 + k;
    if (sp >= 0) {
      int mr = b * LL + (dir ? (LL - 1 - sp) : sp);
      acc += cw[d * 4 + k] * xh[mr * DI + d];
    }
  }
  xc[(dir * NROW + row) * DI + d] = siluf(acc);
}

// ---------------- K3b: x_proj -> x_dbl; dt=softplus; emit B,C (transposed W) ----------------
__global__ __launch_bounds__(256) void k_xproj(
    const float* __restrict__ xc,
    const float* __restrict__ wt_xp, const float* __restrict__ wt_dt,
    const float* __restrict__ dtbf, const float* __restrict__ dtbb,
    float* __restrict__ dt, float* __restrict__ Bm, float* __restrict__ Cm) {
  int dir = blockIdx.y;
  int r0 = blockIdx.x * 16;
  const float* wxp = wt_xp + dir * DI * EP;   // [k][48]
  const float* wdt = wt_dt + dir * RK * DI;   // [j][384]
  const float* dtb = dir ? dtbb : dtbf;
  __shared__ float xs[16][DI];
  __shared__ float xd[16][EP];
  for (int idx = threadIdx.x; idx < 16 * DI; idx += 256) {
    int r = idx / DI, d2 = idx % DI;
    xs[r][d2] = xc[(size_t)(dir * NROW + r0 + r) * DI + d2];
  }
  __syncthreads();
  for (int o = threadIdx.x; o < 16 * EP; o += 256) {
    int r = o / EP, e = o % EP;
    const float* wcol = wxp + e;           // stride EP along k, coalesced across lanes
    const float4* xr = reinterpret_cast<const float4*>(&xs[r][0]);
    float ax = 0.f, ay = 0.f, az = 0.f, aw = 0.f;   // 4 independent chains
    #pragma unroll 4
    for (int q = 0; q < DI / 4; q++) {
      float4 x = xr[q];
      ax += wcol[(4*q+0) * EP] * x.x;
      ay += wcol[(4*q+1) * EP] * x.y;
      az += wcol[(4*q+2) * EP] * x.z;
      aw += wcol[(4*q+3) * EP] * x.w;
    }
    xd[r][e] = (ax + ay) + (az + aw);
  }
  __syncthreads();
  for (int o = threadIdx.x; o < 16 * DI; o += 256) {
    int r = o / DI, d2 = o % DI;
    float a = dtb[d2];
    #pragma unroll
    for (int j = 0; j < RK; j++) a += xd[r][j] * wdt[j * DI + d2];
    a = (a > 20.f) ? a : log1pf(__expf(a));
    dt[(size_t)(dir * NROW + r0 + r) * DI + d2] = a;
  }
  for (int o = threadIdx.x; o < 16 * 32; o += 256) {
    int r = o / 32, j = o % 32;
    float v = xd[r][RK + j];
    if (j < DS) Bm[(size_t)(dir * NROW + r0 + r) * DS + j] = v;
    else        Cm[(size_t)(dir * NROW + r0 + r) * DS + (j - DS)] = v;
  }
}

// ---------------- S1: per-chunk local scan aggregates ----------------
__global__ __launch_bounds__(128) void k_scan1(
    const float* __restrict__ dt, const float* __restrict__ xc,
    const float* __restrict__ Bm,
    const float* __restrict__ Alf, const float* __restrict__ Alb,
    float* __restrict__ S, float* __restrict__ P) {
  int zb = blockIdx.z;              // dir*B + b
  int dir = zb >> 1;
  int d = blockIdx.x * 128 + threadIdx.x;
  int c = blockIdx.y;
  const float* Al = dir ? Alb : Alf;
  float Av[DS];
  {
    const float4* ap = reinterpret_cast<const float4*>(Al + d * DS);
    #pragma unroll
    for (int q = 0; q < 4; q++) {
      float4 a = ap[q];
      Av[4*q+0] = -__expf(a.x); Av[4*q+1] = -__expf(a.y);
      Av[4*q+2] = -__expf(a.z); Av[4*q+3] = -__expf(a.w);
    }
  }
  int rowbase = zb * LL + c * CLEN;
  const float4* Bp4 = reinterpret_cast<const float4*>(Bm + (size_t)rowbase * DS);
  float h[DS];
  #pragma unroll
  for (int n = 0; n < DS; n++) h[n] = 0.f;
  float sdt = 0.f;
  float dtv = dt[(size_t)rowbase * DI + d];
  float xv  = xc[(size_t)rowbase * DI + d];
  #pragma unroll 4
  for (int s = 0; s < CLEN; s++) {
    float dtn_ = 0.f, xn_ = 0.f;
    if (s + 1 < CLEN) {
      dtn_ = dt[(size_t)(rowbase + s + 1) * DI + d];
      xn_  = xc[(size_t)(rowbase + s + 1) * DI + d];
    }
    float4 B0 = Bp4[s*4+0], B1 = Bp4[s*4+1], B2 = Bp4[s*4+2], B3 = Bp4[s*4+3];
    float Bv[DS] = {B0.x,B0.y,B0.z,B0.w, B1.x,B1.y,B1.z,B1.w,
                    B2.x,B2.y,B2.z,B2.w, B3.x,B3.y,B3.z,B3.w};
    float dtx = dtv * xv;
    sdt += dtv;
    #pragma unroll
    for (int n = 0; n < DS; n++) {
      float dA = __expf(dtv * Av[n]);
      h[n] = __fmaf_rn(dA, h[n], dtx * Bv[n]);
    }
    dtv = dtn_; xv = xn_;
  }
  size_t base = ((size_t)(zb * NCH + c) * DI + d) * DS;
  float4* Sp = reinterpret_cast<float4*>(S + base);
  float4* Pp = reinterpret_cast<float4*>(P + base);
  #pragma unroll
  for (int q = 0; q < 4; q++) {
    Sp[q] = make_float4(h[4*q+0], h[4*q+1], h[4*q+2], h[4*q+3]);
    Pp[q] = make_float4(__expf(Av[4*q+0]*sdt), __expf(Av[4*q+1]*sdt),
                        __expf(Av[4*q+2]*sdt), __expf(Av[4*q+3]*sdt));
  }
}

// ---------------- S2: combine carries across chunks (in-place: S -> Hin) ----------------
__global__ __launch_bounds__(256) void k_scan2(
    float* __restrict__ S, const float* __restrict__ P) {
  int g = blockIdx.x * 256 + threadIdx.x;   // 24576 chains
  int zb = g / (DI * DS);
  int rem = g % (DI * DS);
  const int stride = DI * DS;
  size_t base = (size_t)zb * NCH * stride + rem;
  float carry = 0.f;
  for (int c0 = 0; c0 < NCH; c0 += 8) {
    float p8[8], s8[8];
    #pragma unroll
    for (int j = 0; j < 8; j++) {
      p8[j] = P[base + (size_t)(c0 + j) * stride];
      s8[j] = S[base + (size_t)(c0 + j) * stride];
    }
    #pragma unroll
    for (int j = 0; j < 8; j++) {
      S[base + (size_t)(c0 + j) * stride] = carry;      // Hin for chunk c0+j
      carry = __fmaf_rn(p8[j], carry, s8[j]);
    }
  }
}

// ---------------- S3: final per-chunk scan + y ----------------
__global__ __launch_bounds__(128) void k_scan3(
    const float* __restrict__ dt, const float* __restrict__ xc,
    const float* __restrict__ Bm, const float* __restrict__ Cm,
    const float* __restrict__ z, const float* __restrict__ Hin,
    const float* __restrict__ Alf, const float* __restrict__ Alb,
    const float* __restrict__ Df, const float* __restrict__ Db,
    float* __restrict__ y) {
  int zb = blockIdx.z;
  int dir = zb >> 1, b = zb & 1;
  int d = blockIdx.x * 128 + threadIdx.x;
  int c = blockIdx.y;
  const float* Al = dir ? Alb : Alf;
  const float* Dp = dir ? Db : Df;
  float Av[DS];
  {
    const float4* ap = reinterpret_cast<const float4*>(Al + d * DS);
    #pragma unroll
    for (int q = 0; q < 4; q++) {
      float4 a = ap[q];
      Av[4*q+0] = -__expf(a.x); Av[4*q+1] = -__expf(a.y);
      Av[4*q+2] = -__expf(a.z); Av[4*q+3] = -__expf(a.w);
    }
  }
  float Dv = Dp[d];
  int rowbase = zb * LL + c * CLEN;
  const float4* Bp4 = reinterpret_cast<const float4*>(Bm + (size_t)rowbase * DS);
  const float4* Cp4 = reinterpret_cast<const float4*>(Cm + (size_t)rowbase * DS);
  size_t base = ((size_t)(zb * NCH + c) * DI + d) * DS;
  float h[DS];
  {
    const float4* hp = reinterpret_cast<const float4*>(Hin + base);
    #pragma unroll
    for (int q = 0; q < 4; q++) {
      float4 a = hp[q];
      h[4*q+0] = a.x; h[4*q+1] = a.y; h[4*q+2] = a.z; h[4*q+3] = a.w;
    }
  }
  float dtv = dt[(size_t)rowbase * DI + d];
  float xv  = xc[(size_t)rowbase * DI + d];
  #pragma unroll 4
  for (int s = 0; s < CLEN; s++) {
    float dtn_ = 0.f, xn_ = 0.f;
    if (s + 1 < CLEN) {
      dtn_ = dt[(size_t)(rowbase + s + 1) * DI + d];
      xn_  = xc[(size_t)(rowbase + s + 1) * DI + d];
    }
    float4 B0 = Bp4[s*4+0], B1 = Bp4[s*4+1], B2 = Bp4[s*4+2], B3 = Bp4[s*4+3];
    float Bv[DS] = {B0.x,B0.y,B0.z,B0.w, B1.x,B1.y,B1.z,B1.w,
                    B2.x,B2.y,B2.z,B2.w, B3.x,B3.y,B3.z,B3.w};
    float4 C0 = Cp4[s*4+0], C1 = Cp4[s*4+1], C2 = Cp4[s*4+2], C3 = Cp4[s*4+3];
    float Cv[DS] = {C0.x,C0.y,C0.z,C0.w, C1.x,C1.y,C1.z,C1.w,
                    C2.x,C2.y,C2.z,C2.w, C3.x,C3.y,C3.z,C3.w};
    float dtx = dtv * xv;
    float acc = xv * Dv;
    #pragma unroll
    for (int n = 0; n < DS; n++) {
      float dA = __expf(dtv * Av[n]);
      h[n] = __fmaf_rn(dA, h[n], dtx * Bv[n]);
      acc = __fmaf_rn(h[n], Cv[n], acc);
    }
    int sg = c * CLEN + s;
    int mr = b * LL + (dir ? (LL - 1 - sg) : sg);
    float zv = z[(size_t)mr * DI + d];
    y[(size_t)(rowbase + s) * DI + d] = acc * siluf(zv);
    dtv = dtn_; xv = xn_;
  }
}

// ---------------- K5: out = (y_f + rev(y_b)) @ out_proj^T (transposed W) ----------------
// 8-row tiles -> 512 blocks; unroll-4 weight prefetch
__global__ __launch_bounds__(192) void k_outproj(
    const float* __restrict__ y, const float* __restrict__ wt,
    float* __restrict__ out) {
  __shared__ float ys[DI][8];     // [k][r]
  int r0 = blockIdx.x * 8;        // memory-order rows
  for (int idx = threadIdx.x; idx < 8 * DI; idx += 192) {
    int r = idx & 7, k = idx >> 3;    // lane-contiguous LDS store
    int row = r0 + r;
    int b = row >> 11, l = row & (LL - 1);
    float vf = y[(size_t)(b * LL + l) * DI + k];
    float vb = y[(size_t)((2 + b) * LL + (LL - 1 - l)) * DI + k];
    ys[k][r] = vf + vb;
  }
  __syncthreads();
  int c = threadIdx.x;            // 192 threads = 192 output cols
  const float* wc = wt + c;       // stride 192 along k, coalesced across lanes
  float acc[8];
  #pragma unroll
  for (int i = 0; i < 8; i++) acc[i] = 0.f;
  for (int k = 0; k < DI; k += 4) {
    float w0 = wc[(k+0) * DM];
    float w1 = wc[(k+1) * DM];
    float w2 = wc[(k+2) * DM];
    float w3 = wc[(k+3) * DM];
    float wv4[4] = {w0, w1, w2, w3};
    #pragma unroll
    for (int kk = 0; kk < 4; kk++) {
      float wv = wv4[kk];
      const float4* xr = reinterpret_cast<const float4*>(&ys[k + kk][0]);
      float4 a0 = xr[0], a1 = xr[1];
      acc[0] += wv * a0.x; acc[1] += wv * a0.y;
      acc[2] += wv * a0.z; acc[3] += wv * a0.w;
      acc[4] += wv * a1.x; acc[5] += wv * a1.y;
      acc[6] += wv * a1.z; acc[7] += wv * a1.w;
    }
  }
  #pragma unroll
  for (int r2 = 0; r2 < 8; r2++) out[(r0 + r2) * DM + c] = acc[r2];
}

extern "C" void kernel_launch(void* const* d_in, const int* in_sizes, int n_in,
                              void* d_out, int out_size, void* d_ws, size_t ws_size,
                              hipStream_t stream) {
  const float* hid  = (const float*)d_in[0];
  const float* res  = (const float*)d_in[1];
  const float* nw   = (const float*)d_in[2];
  const float* wip  = (const float*)d_in[3];
  const float* wop  = (const float*)d_in[4];
  const float* cwf  = (const float*)d_in[5];
  const float* cbf  = (const float*)d_in[6];
  const float* xpwf = (const float*)d_in[7];
  const float* dtwf = (const float*)d_in[8];
  const float* dtbf = (const float*)d_in[9];
  const float* Alf  = (const float*)d_in[10];
  const float* Df   = (const float*)d_in[11];
  const float* cwb  = (const float*)d_in[12];
  const float* cbb  = (const float*)d_in[13];
  const float* xpwb = (const float*)d_in[14];
  const float* dtwb = (const float*)d_in[15];
  const float* dtbb = (const float*)d_in[16];
  const float* Alb  = (const float*)d_in[17];
  const float* Db   = (const float*)d_in[18];

  float* out_p  = (float*)d_out;                  // (B,L,192)
  float* resid  = out_p + NROW * DM;              // (B,L,192)

  float* ws = (float*)d_ws;
  float* xn  = ws;                       // 786432
  float* xh  = xn  + NROW * DM;          // 1572864
  float* zz  = xh  + NROW * DI;          // 1572864
  float* xc  = zz  + NROW * DI;          // 2*1572864
  float* dt  = xc  + 2 * NROW * DI;      // 2*1572864
  float* Bm  = dt  + 2 * NROW * DI;      // 2*65536
  float* Cm  = Bm  + 2 * NROW * DS;      // 2*65536
  float* yy  = Cm  + 2 * NROW * DS;      // 2*1572864
  float* S   = yy  + 2 * NROW * DI;      // 1572864
  float* P   = S   + 2 * BB * NCH * DI * DS;  // 1572864
  float* wt_in  = P     + 2 * BB * NCH * DI * DS;
  float* wt_out = wt_in  + N_IN;
  float* wt_xp  = wt_out + N_OUT;
  float* wt_dt  = wt_xp  + N_XP;

  k_wprep<<<(N_PREP + 255) / 256, 256, 0, stream>>>(wip, wop, xpwf, xpwb, dtwf, dtwb,
                                                    wt_in, wt_out, wt_xp, wt_dt);
  k_rmsnorm<<<NROW / 4, 256, 0, stream>>>(hid, res, nw, resid, xn);
  k_inproj<<<dim3(NROW / 16, 3), 256, 0, stream>>>(xn, wt_in, xh, zz);
  k_conv<<<dim3(NROW * DI / 256, 2), 256, 0, stream>>>(xh, cwf, cbf, cwb, cbb, xc);
  k_xproj<<<dim3(NROW / 16, 2), 256, 0, stream>>>(xc, wt_xp, wt_dt, dtbf, dtbb,
                                                  dt, Bm, Cm);
  k_scan1<<<dim3(DI / 128, NCH, 2 * BB), 128, 0, stream>>>(dt, xc, Bm, Alf, Alb, S, P);
  k_scan2<<<(2 * BB * DI * DS) / 256, 256, 0, stream>>>(S, P);
  k_scan3<<<dim3(DI / 128, NCH, 2 * BB), 128, 0, stream>>>(dt, xc, Bm, Cm, zz, S,
                                                           Alf, Alb, Df, Db, yy);
  k_outproj<<<NROW / 8, 192, 0, stream>>>(yy, wt_out, out_p);
}